// Round 2
// baseline (148.054 us; speedup 1.0000x reference)
//
#include <hip/hip_runtime.h>
#include <hip/hip_bf16.h>
#include <stdint.h>

namespace {

constexpr int Bb = 2;
constexpr int Hh = 16;
constexpr int Ss = 2048;
constexpr int Dd = 64;
constexpr int KT = 64;                   // keys per stored tile
constexpr int NT = Ss / KT;              // 32 stored key tiles
constexpr int TILE_BYTES = KT * Dd * 2;  // 8192 B per bf16 tile
constexpr int BH_BYTES = NT * TILE_BYTES;
constexpr size_t KPRE_BYTES = (size_t)Bb * Hh * Ss * Dd * 2;  // 8 MB
constexpr size_t VPRE_OFF = KPRE_BYTES;
constexpr size_t MASK_OFF = 2 * KPRE_BYTES;
constexpr size_t WS_NEED = MASK_OFF + (size_t)Bb * NT * 8;

typedef __bf16 bf16x8 __attribute__((ext_vector_type(8)));
typedef float floatx4 __attribute__((ext_vector_type(4)));

typedef __attribute__((address_space(1))) const unsigned int guint;
typedef __attribute__((address_space(3))) unsigned int luint;

__device__ __forceinline__ void g2lds16(const void* g, void* l) {
  __builtin_amdgcn_global_load_lds((guint*)g, (luint*)l, 16, 0, 0);
}

// ---------------- preprocess3 (unchanged, validated) ----------------
__global__ __launch_bounds__(256) void preprocess3(
    const float* __restrict__ K, const float* __restrict__ V,
    const int* __restrict__ mask, uint8_t* __restrict__ ws)
{
  const int tid = threadIdx.x;
  const int kt = blockIdx.x;
  const int bh = blockIdx.y;

  if (blockIdx.z == 0) {
    // ---- K: convert + swizzled store (both sides contiguous per wave) ----
    const int c = tid & 7;
#pragma unroll
    for (int half = 0; half < 2; ++half) {
      const int row = (tid >> 3) + half * 32;
      const float4* src = (const float4*)(K + ((size_t)bh * 2048 + kt * 64 + row) * 64 + c * 8);
      const float4 a = src[0], b2 = src[1];
      bf16x8 pk;
      pk[0] = (__bf16)a.x;  pk[1] = (__bf16)a.y;  pk[2] = (__bf16)a.z;  pk[3] = (__bf16)a.w;
      pk[4] = (__bf16)b2.x; pk[5] = (__bf16)b2.y; pk[6] = (__bf16)b2.z; pk[7] = (__bf16)b2.w;
      uint8_t* dst = ws + (size_t)bh * BH_BYTES + kt * TILE_BYTES + row * 128 + ((c ^ (row & 7)) << 4);
      *(bf16x8*)dst = pk;
    }
    if (bh == 0 && kt < 16) {  // mask ballots: 16 blocks cover Bb*Ss = 4096
      const int i = kt * 256 + tid;
      const int bb = i >> 11, key = i & 2047;
      const unsigned long long bal = __ballot(mask[bb * 2048 + key] != 0);
      if ((key & 63) == 0)
        ((unsigned long long*)(ws + MASK_OFF))[bb * NT + (key >> 6)] = bal;
    }
    return;
  }

  // ---- V: coalesced load -> LDS -> transposed swizzled store ----
  __shared__ float Vsh[64 * 68];
#pragma unroll
  for (int i = 0; i < 4; ++i) {
    const int vt = tid + 256 * i;
    const int row = vt >> 4, c4 = vt & 15;
    const float4 v4 = *(const float4*)(V + ((size_t)bh * 2048 + kt * 64 + row) * 64 + c4 * 4);
    *(float4*)&Vsh[row * 68 + c4 * 4] = v4;
  }
  __syncthreads();
  {
    const int c16 = tid & 7;
    const int s2 = c16 & 1, q = c16 >> 1;
    const int k0 = 32 * s2 + 4 * q;
#pragma unroll
    for (int half = 0; half < 2; ++half) {
      const int d = (tid >> 3) + half * 32;
      bf16x8 pv;
#pragma unroll
      for (int j = 0; j < 4; ++j) {
        pv[j]     = (__bf16)Vsh[(k0 + j) * 68 + d];
        pv[4 + j] = (__bf16)Vsh[(k0 + 16 + j) * 68 + d];
      }
      uint8_t* dst = ws + VPRE_OFF + (size_t)bh * BH_BYTES + kt * TILE_BYTES + d * 128 + ((c16 ^ (d & 7)) << 4);
      *(bf16x8*)dst = pv;
    }
  }
}

// -10000 * log2(e): reference's masked_fill value, in exp2 domain.
#define NEGM (-14426.950408889634f)
#define MFMA16 __builtin_amdgcn_mfma_f32_16x16x32_bf16

// ---------------- fused attention, K-split (flash-decoding in-block) ------
// Same validated memory structure (S^T = K.Q^T, mask-as-C-bias, PV K=32,
// dual q-streams sharing LDS reads, g2lds double-buffer).
// NEW: 8 waves/block = 2 key-groups x 4 q-waves. Group g handles key tiles
// g*16..g*16+15 at KVBLK=64 (one stored tile per iter), own double-buffered
// K/V LDS (2x2x8KB per tensor = 64 KiB total). Total waves 2048->4096 ->
// 4 waves/SIMD (was 2): the kernel is latency-bound (no pipe >50%), so
// doubled occupancy hides ds_read/MFMA dependency chains + barrier drains.
// No running max exists (scores bounded, masked keys underflow to 0), so
// the K-split merge is a pure (O,l) add in LDS at the end - exact.
__global__ __launch_bounds__(512, 4) void attn_fused8(
    const float* __restrict__ Q, const uint8_t* __restrict__ ws,
    float* __restrict__ Out)
{
  const int tid  = threadIdx.x;
  const int wave = tid >> 6;
  const int kgrp = wave >> 2;   // 0: keys 0..1023, 1: keys 1024..2047
  const int wq   = wave & 3;    // q-position within block
  const int lane = tid & 63;
  const int ln   = lane & 15;
  const int quad = lane >> 4;

  const int bh   = blockIdx.x;  // 0..31 (same bh -> same XCD for L2 reuse)
  const int qblk = blockIdx.y;  // 0..15
  const int b    = bh >> 4;

  const float* Qb = Q + (size_t)bh * Ss * Dd;
  float*       Ob = Out + (size_t)bh * Ss * Dd;
  const uint8_t* Kpre = ws + (size_t)bh * BH_BYTES + (size_t)kgrp * 16 * TILE_BYTES;
  const uint8_t* Vpre = ws + VPRE_OFF + (size_t)bh * BH_BYTES + (size_t)kgrp * 16 * TILE_BYTES;
  const unsigned long long* Mbits =
      (const unsigned long long*)(ws + MASK_OFF) + b * NT + kgrp * 16;

  __shared__ __align__(16) __bf16 Klds[2][2][64 * Dd];   // [kgrp][buf] 4x8KB
  __shared__ __align__(16) __bf16 Vlds[2][2][64 * Dd];   // [kgrp][buf] 4x8KB

  const int q0A = qblk * 128 + wq * 32;
  const int q0B = q0A + 16;

  // Q B-frags, pre-scaled by 1/8*log2(e). B[k=quad*8+j][n=ln] = Qs[q][d].
  const float QS = 0.125f * 1.44269504088896340736f;
  bf16x8 aqA0, aqA1, aqB0, aqB1;
  {
    const float* qpA = Qb + (size_t)(q0A + ln) * Dd + quad * 8;
    const float* qpB = Qb + (size_t)(q0B + ln) * Dd + quad * 8;
#pragma unroll
    for (int j = 0; j < 8; ++j) {
      aqA0[j] = (__bf16)(qpA[j] * QS);
      aqA1[j] = (__bf16)(qpA[32 + j] * QS);
      aqB0[j] = (__bf16)(qpB[j] * QS);
      aqB1[j] = (__bf16)(qpB[32 + j] * QS);
    }
  }

  floatx4 oA[4], oB[4];    // O^T C-layout: d = nd*16+quad*4+r, q = ln
  floatx4 laccA = (floatx4){0.f, 0.f, 0.f, 0.f};
  floatx4 laccB = (floatx4){0.f, 0.f, 0.f, 0.f};
#pragma unroll
  for (int nd = 0; nd < 4; ++nd) {
    oA[nd] = (floatx4){0.f, 0.f, 0.f, 0.f};
    oB[nd] = (floatx4){0.f, 0.f, 0.f, 0.f};
  }

  const int swz0 = (quad ^ (ln & 7)) << 4;
  const int swz1 = ((quad + 4) ^ (ln & 7)) << 4;
  const int soff = wq * 1024 + lane * 16;  // group-level staging offset

  // prologue: stage tile 0 of this group into buffer 0 (8 KB per tensor)
#pragma unroll
  for (int i = 0; i < 2; ++i) {
    g2lds16(Kpre + soff + i * 4096, (uint8_t*)Klds[kgrp][0] + soff + i * 4096);
    g2lds16(Vpre + soff + i * 4096, (uint8_t*)Vlds[kgrp][0] + soff + i * 4096);
  }

  for (int it = 0; it < 16; ++it) {
    const int cur = it & 1;
    __syncthreads();  // closes prev-iter reads + drains this buf's g2lds

    if (it + 1 < 16) {
      const uint8_t* kg = Kpre + (it + 1) * TILE_BYTES;
      const uint8_t* vg = Vpre + (it + 1) * TILE_BYTES;
      uint8_t* kl = (uint8_t*)Klds[kgrp][cur ^ 1];
      uint8_t* vl = (uint8_t*)Vlds[kgrp][cur ^ 1];
#pragma unroll
      for (int i = 0; i < 2; ++i) {
        g2lds16(kg + soff + i * 4096, kl + soff + i * 4096);
        g2lds16(vg + soff + i * 4096, vl + soff + i * 4096);
      }
    }

    const unsigned long long mb = Mbits[it];

    const uint8_t* Kb = (const uint8_t*)Klds[kgrp][cur];
    const uint8_t* Vb = (const uint8_t*)Vlds[kgrp][cur];

    // fragment read helpers (fully unrolled -> constant offsets)
    auto loadK = [&](int sub, bf16x8& b0, bf16x8& b1) {  // sub 0..3
      const uint8_t* krow = Kb + (sub * 16 + ln) * 128;
      b0 = *(const bf16x8*)(krow + swz0);
      b1 = *(const bf16x8*)(krow + swz1);
    };
    auto loadV = [&](int s2, bf16x8* w) {
#pragma unroll
      for (int nd = 0; nd < 4; ++nd) {
        const uint8_t* vrow = Vb + (nd * 16 + ln) * 128;
        w[nd] = *(const bf16x8*)(vrow + (((quad * 2 + s2) ^ (ln & 7)) << 4));
      }
    };

    __builtin_amdgcn_s_setprio(1);

    // register double-buffered fragment pipeline over pairs p = s2 = 0..1
    bf16x8 kf0[2][2], kf1[2][2];  // [p][subtile-in-pair]
    bf16x8 vf[2][4];              // [p][nd]
    loadK(0, kf0[0][0], kf1[0][0]);
    loadK(1, kf0[0][1], kf1[0][1]);
    loadV(0, vf[0]);

#pragma unroll
    for (int p = 0; p < 2; ++p) {
      if (p == 0) {
        loadK(2, kf0[1][0], kf1[1][0]);
        loadK(3, kf0[1][1], kf1[1][1]);
        loadV(1, vf[1]);
      }

      // per-key mask bias for subtiles 2p, 2p+1 (key = 16*sub+quad*4+r)
      const uint32_t bits0 = (uint32_t)(mb >> ((2 * p) * 16 + quad * 4));
      const uint32_t bits1 = (uint32_t)(mb >> ((2 * p + 1) * 16 + quad * 4));
      floatx4 sA0, sA1, sB0, sB1;
#pragma unroll
      for (int r = 0; r < 4; ++r) {
        const float b0v = ((bits0 >> r) & 1) ? NEGM : 0.f;
        const float b1v = ((bits1 >> r) & 1) ? NEGM : 0.f;
        sA0[r] = b0v; sB0[r] = b0v;
        sA1[r] = b1v; sB1[r] = b1v;
      }

      // ---- S^T for pair p: 8 MFMAs ----
      sA0 = MFMA16(kf0[p][0], aqA0, sA0, 0, 0, 0);
      sA0 = MFMA16(kf1[p][0], aqA1, sA0, 0, 0, 0);
      sB0 = MFMA16(kf0[p][0], aqB0, sB0, 0, 0, 0);
      sB0 = MFMA16(kf1[p][0], aqB1, sB0, 0, 0, 0);
      sA1 = MFMA16(kf0[p][1], aqA0, sA1, 0, 0, 0);
      sA1 = MFMA16(kf1[p][1], aqA1, sA1, 0, 0, 0);
      sB1 = MFMA16(kf0[p][1], aqB0, sB1, 0, 0, 0);
      sB1 = MFMA16(kf1[p][1], aqB1, sB1, 0, 0, 0);

      // ---- exp2 (masked -> exact 0 via underflow) + partial l + pack ----
      bf16x8 bpA, bpB;
#pragma unroll
      for (int r = 0; r < 4; ++r) {
        const float pA0 = __builtin_amdgcn_exp2f(sA0[r]);
        const float pA1 = __builtin_amdgcn_exp2f(sA1[r]);
        const float pB0 = __builtin_amdgcn_exp2f(sB0[r]);
        const float pB1 = __builtin_amdgcn_exp2f(sB1[r]);
        laccA[r] += pA0 + pA1;
        laccB[r] += pB0 + pB1;
        bpA[r] = (__bf16)pA0; bpA[4 + r] = (__bf16)pA1;
        bpB[r] = (__bf16)pB0; bpB[4 + r] = (__bf16)pB1;
      }

      // ---- O^T += V^T . P^T for pair p: 8 MFMAs ----
#pragma unroll
      for (int nd = 0; nd < 4; ++nd) {
        oA[nd] = MFMA16(vf[p][nd], bpA, oA[nd], 0, 0, 0);
        oB[nd] = MFMA16(vf[p][nd], bpB, oB[nd], 0, 0, 0);
      }
    }
    __builtin_amdgcn_s_setprio(0);
  }

  // ---- partial l reduce across quads ----
  float lA = (laccA[0] + laccA[1]) + (laccA[2] + laccA[3]);
  float lB = (laccB[0] + laccB[1]) + (laccB[2] + laccB[3]);
  lA += __shfl_xor(lA, 16); lA += __shfl_xor(lA, 32);
  lB += __shfl_xor(lB, 16); lB += __shfl_xor(lB, 32);

  // ---- K-split merge: group 1 -> LDS, group 0 adds + normalizes + stores.
  // Staging LDS is dead now. Chunk-XOR swizzle keeps b128 traffic 2-way.
  __syncthreads();  // all LDS tile reads complete before reuse
  float* sm = (float*)&Klds[0][0][0];   // 8192 floats = 32 KB
  float* sl = (float*)&Vlds[0][0][0];
  const int mbase = (wq * 64 + lane) * 32;  // 32 floats (8x16B chunks) per lane
  const int sw = lane & 7;
  if (kgrp == 1) {
#pragma unroll
    for (int nd = 0; nd < 4; ++nd) {
      *(floatx4*)&sm[mbase + ((nd ^ sw) << 2)]       = oA[nd];
      *(floatx4*)&sm[mbase + (((4 + nd) ^ sw) << 2)] = oB[nd];
    }
    sl[(wq * 64 + lane) * 2 + 0] = lA;
    sl[(wq * 64 + lane) * 2 + 1] = lB;
  }
  __syncthreads();
  if (kgrp == 0) {
    lA += sl[(wq * 64 + lane) * 2 + 0];
    lB += sl[(wq * 64 + lane) * 2 + 1];
    const float iA = 1.0f / lA, iB = 1.0f / lB;
#pragma unroll
    for (int nd = 0; nd < 4; ++nd) {
      floatx4 pA = *(const floatx4*)&sm[mbase + ((nd ^ sw) << 2)];
      floatx4 pB = *(const floatx4*)&sm[mbase + (((4 + nd) ^ sw) << 2)];
      pA += oA[nd];
      pB += oB[nd];
      float4 wv;
      wv.x = pA[0] * iA; wv.y = pA[1] * iA;
      wv.z = pA[2] * iA; wv.w = pA[3] * iA;
      *(float4*)(Ob + (size_t)(q0A + ln) * Dd + nd * 16 + quad * 4) = wv;
      wv.x = pB[0] * iB; wv.y = pB[1] * iB;
      wv.z = pB[2] * iB; wv.w = pB[3] * iB;
      *(float4*)(Ob + (size_t)(q0B + ln) * Dd + nd * 16 + quad * 4) = wv;
    }
  }
}

}  // namespace

extern "C" void kernel_launch(void* const* d_in, const int* in_sizes, int n_in,
                              void* d_out, int out_size, void* d_ws, size_t ws_size,
                              hipStream_t stream) {
  const float* Q   = (const float*)d_in[0];
  const float* K   = (const float*)d_in[1];
  const float* V   = (const float*)d_in[2];
  const int*  mask = (const int*)d_in[3];
  float* Out = (float*)d_out;

  preprocess3<<<dim3(32, 32, 2), 256, 0, stream>>>(K, V, mask, (uint8_t*)d_ws);
  attn_fused8<<<dim3(Bb * Hh, Ss / 128), 512, 0, stream>>>(Q, (const uint8_t*)d_ws, Out);
  (void)ws_size; (void)in_sizes; (void)n_in; (void)out_size;
}

// Round 3
// 146.520 us; speedup vs baseline: 1.0105x; 1.0105x over previous
//
#include <hip/hip_runtime.h>
#include <hip/hip_bf16.h>
#include <stdint.h>

namespace {

constexpr int Bb = 2;
constexpr int Hh = 16;
constexpr int Ss = 2048;
constexpr int Dd = 64;
constexpr int KT = 64;                   // keys per stored tile
constexpr int NT = Ss / KT;              // 32 stored key tiles
constexpr int TILE_BYTES = KT * Dd * 2;  // 8192 B per bf16 tile
constexpr int BH_BYTES = NT * TILE_BYTES;
constexpr size_t KPRE_BYTES = (size_t)Bb * Hh * Ss * Dd * 2;  // 8 MB
constexpr size_t VPRE_OFF = KPRE_BYTES;
constexpr size_t MASK_OFF = 2 * KPRE_BYTES;
constexpr size_t WS_NEED = MASK_OFF + (size_t)Bb * NT * 8;

typedef __bf16 bf16x8 __attribute__((ext_vector_type(8)));
typedef float floatx4 __attribute__((ext_vector_type(4)));

typedef __attribute__((address_space(1))) const unsigned int guint;
typedef __attribute__((address_space(3))) unsigned int luint;

__device__ __forceinline__ void g2lds16(const void* g, void* l) {
  __builtin_amdgcn_global_load_lds((guint*)g, (luint*)l, 16, 0, 0);
}

// ---------------- preprocess3 (unchanged, validated) ----------------
__global__ __launch_bounds__(256) void preprocess3(
    const float* __restrict__ K, const float* __restrict__ V,
    const int* __restrict__ mask, uint8_t* __restrict__ ws)
{
  const int tid = threadIdx.x;
  const int kt = blockIdx.x;
  const int bh = blockIdx.y;

  if (blockIdx.z == 0) {
    // ---- K: convert + swizzled store (both sides contiguous per wave) ----
    const int c = tid & 7;
#pragma unroll
    for (int half = 0; half < 2; ++half) {
      const int row = (tid >> 3) + half * 32;
      const float4* src = (const float4*)(K + ((size_t)bh * 2048 + kt * 64 + row) * 64 + c * 8);
      const float4 a = src[0], b2 = src[1];
      bf16x8 pk;
      pk[0] = (__bf16)a.x;  pk[1] = (__bf16)a.y;  pk[2] = (__bf16)a.z;  pk[3] = (__bf16)a.w;
      pk[4] = (__bf16)b2.x; pk[5] = (__bf16)b2.y; pk[6] = (__bf16)b2.z; pk[7] = (__bf16)b2.w;
      uint8_t* dst = ws + (size_t)bh * BH_BYTES + kt * TILE_BYTES + row * 128 + ((c ^ (row & 7)) << 4);
      *(bf16x8*)dst = pk;
    }
    if (bh == 0 && kt < 16) {  // mask ballots: 16 blocks cover Bb*Ss = 4096
      const int i = kt * 256 + tid;
      const int bb = i >> 11, key = i & 2047;
      const unsigned long long bal = __ballot(mask[bb * 2048 + key] != 0);
      if ((key & 63) == 0)
        ((unsigned long long*)(ws + MASK_OFF))[bb * NT + (key >> 6)] = bal;
    }
    return;
  }

  // ---- V: coalesced load -> LDS -> transposed swizzled store ----
  __shared__ float Vsh[64 * 68];
#pragma unroll
  for (int i = 0; i < 4; ++i) {
    const int vt = tid + 256 * i;
    const int row = vt >> 4, c4 = vt & 15;
    const float4 v4 = *(const float4*)(V + ((size_t)bh * 2048 + kt * 64 + row) * 64 + c4 * 4);
    *(float4*)&Vsh[row * 68 + c4 * 4] = v4;
  }
  __syncthreads();
  {
    const int c16 = tid & 7;
    const int s2 = c16 & 1, q = c16 >> 1;
    const int k0 = 32 * s2 + 4 * q;
#pragma unroll
    for (int half = 0; half < 2; ++half) {
      const int d = (tid >> 3) + half * 32;
      bf16x8 pv;
#pragma unroll
      for (int j = 0; j < 4; ++j) {
        pv[j]     = (__bf16)Vsh[(k0 + j) * 68 + d];
        pv[4 + j] = (__bf16)Vsh[(k0 + 16 + j) * 68 + d];
      }
      uint8_t* dst = ws + VPRE_OFF + (size_t)bh * BH_BYTES + kt * TILE_BYTES + d * 128 + ((c16 ^ (d & 7)) << 4);
      *(bf16x8*)dst = pv;
    }
  }
}

// -10000 * log2(e): reference's masked_fill value, in exp2 domain.
#define NEGM (-14426.950408889634f)
#define MFMA16 __builtin_amdgcn_mfma_f32_16x16x32_bf16

// ---------------- fused attention, K-split (flash-decoding in-block) ------
// Same validated memory structure (S^T = K.Q^T, mask-as-C-bias, PV K=32,
// dual q-streams sharing LDS reads, g2lds double-buffer).
// 8 waves/block = 2 key-groups x 4 q-waves; merge partial (O,l) in LDS.
// R2 LESSON: __launch_bounds__(512,4) capped VGPRs at 64 (arg-2 behaves as
// min-BLOCKS-per-CU here: 4 blocks x 8 waves = 32 waves/CU -> 64-reg budget)
// and the ~48 regs of spill cost +33 MB of scratch HBM traffic. (512,2)
// gives a >=128 cap; natural usage ~112 -> no spill, 16 waves/CU
// (2 blocks/CU, LDS-limited), 4 waves/SIMD.
__global__ __launch_bounds__(512, 2) void attn_fused8(
    const float* __restrict__ Q, const uint8_t* __restrict__ ws,
    float* __restrict__ Out)
{
  const int tid  = threadIdx.x;
  const int wave = tid >> 6;
  const int kgrp = wave >> 2;   // 0: keys 0..1023, 1: keys 1024..2047
  const int wq   = wave & 3;    // q-position within block
  const int lane = tid & 63;
  const int ln   = lane & 15;
  const int quad = lane >> 4;

  const int bh   = blockIdx.x;  // 0..31 (same bh -> same XCD for L2 reuse)
  const int qblk = blockIdx.y;  // 0..15
  const int b    = bh >> 4;

  const float* Qb = Q + (size_t)bh * Ss * Dd;
  float*       Ob = Out + (size_t)bh * Ss * Dd;
  const uint8_t* Kpre = ws + (size_t)bh * BH_BYTES + (size_t)kgrp * 16 * TILE_BYTES;
  const uint8_t* Vpre = ws + VPRE_OFF + (size_t)bh * BH_BYTES + (size_t)kgrp * 16 * TILE_BYTES;
  const unsigned long long* Mbits =
      (const unsigned long long*)(ws + MASK_OFF) + b * NT + kgrp * 16;

  __shared__ __align__(16) __bf16 Klds[2][2][64 * Dd];   // [kgrp][buf] 4x8KB
  __shared__ __align__(16) __bf16 Vlds[2][2][64 * Dd];   // [kgrp][buf] 4x8KB

  const int q0A = qblk * 128 + wq * 32;
  const int q0B = q0A + 16;

  // Q B-frags, pre-scaled by 1/8*log2(e). B[k=quad*8+j][n=ln] = Qs[q][d].
  const float QS = 0.125f * 1.44269504088896340736f;
  bf16x8 aqA0, aqA1, aqB0, aqB1;
  {
    const float* qpA = Qb + (size_t)(q0A + ln) * Dd + quad * 8;
    const float* qpB = Qb + (size_t)(q0B + ln) * Dd + quad * 8;
#pragma unroll
    for (int j = 0; j < 8; ++j) {
      aqA0[j] = (__bf16)(qpA[j] * QS);
      aqA1[j] = (__bf16)(qpA[32 + j] * QS);
      aqB0[j] = (__bf16)(qpB[j] * QS);
      aqB1[j] = (__bf16)(qpB[32 + j] * QS);
    }
  }

  floatx4 oA[4], oB[4];    // O^T C-layout: d = nd*16+quad*4+r, q = ln
  floatx4 laccA = (floatx4){0.f, 0.f, 0.f, 0.f};
  floatx4 laccB = (floatx4){0.f, 0.f, 0.f, 0.f};
#pragma unroll
  for (int nd = 0; nd < 4; ++nd) {
    oA[nd] = (floatx4){0.f, 0.f, 0.f, 0.f};
    oB[nd] = (floatx4){0.f, 0.f, 0.f, 0.f};
  }

  const int swz0 = (quad ^ (ln & 7)) << 4;
  const int swz1 = ((quad + 4) ^ (ln & 7)) << 4;
  const int soff = wq * 1024 + lane * 16;  // group-level staging offset

  // prologue: stage tile 0 of this group into buffer 0 (8 KB per tensor)
#pragma unroll
  for (int i = 0; i < 2; ++i) {
    g2lds16(Kpre + soff + i * 4096, (uint8_t*)Klds[kgrp][0] + soff + i * 4096);
    g2lds16(Vpre + soff + i * 4096, (uint8_t*)Vlds[kgrp][0] + soff + i * 4096);
  }

  for (int it = 0; it < 16; ++it) {
    const int cur = it & 1;
    __syncthreads();  // closes prev-iter reads + drains this buf's g2lds

    if (it + 1 < 16) {
      const uint8_t* kg = Kpre + (it + 1) * TILE_BYTES;
      const uint8_t* vg = Vpre + (it + 1) * TILE_BYTES;
      uint8_t* kl = (uint8_t*)Klds[kgrp][cur ^ 1];
      uint8_t* vl = (uint8_t*)Vlds[kgrp][cur ^ 1];
#pragma unroll
      for (int i = 0; i < 2; ++i) {
        g2lds16(kg + soff + i * 4096, kl + soff + i * 4096);
        g2lds16(vg + soff + i * 4096, vl + soff + i * 4096);
      }
    }

    const unsigned long long mb = Mbits[it];

    const uint8_t* Kb = (const uint8_t*)Klds[kgrp][cur];
    const uint8_t* Vb = (const uint8_t*)Vlds[kgrp][cur];

    // fragment read helpers (fully unrolled -> constant offsets)
    auto loadK = [&](int sub, bf16x8& b0, bf16x8& b1) {  // sub 0..3
      const uint8_t* krow = Kb + (sub * 16 + ln) * 128;
      b0 = *(const bf16x8*)(krow + swz0);
      b1 = *(const bf16x8*)(krow + swz1);
    };
    auto loadV = [&](int s2, bf16x8* w) {
#pragma unroll
      for (int nd = 0; nd < 4; ++nd) {
        const uint8_t* vrow = Vb + (nd * 16 + ln) * 128;
        w[nd] = *(const bf16x8*)(vrow + (((quad * 2 + s2) ^ (ln & 7)) << 4));
      }
    };

    __builtin_amdgcn_s_setprio(1);

    // register double-buffered fragment pipeline over pairs p = s2 = 0..1
    bf16x8 kf0[2][2], kf1[2][2];  // [p][subtile-in-pair]
    bf16x8 vf[2][4];              // [p][nd]
    loadK(0, kf0[0][0], kf1[0][0]);
    loadK(1, kf0[0][1], kf1[0][1]);
    loadV(0, vf[0]);

#pragma unroll
    for (int p = 0; p < 2; ++p) {
      if (p == 0) {
        loadK(2, kf0[1][0], kf1[1][0]);
        loadK(3, kf0[1][1], kf1[1][1]);
        loadV(1, vf[1]);
      }

      // per-key mask bias for subtiles 2p, 2p+1 (key = 16*sub+quad*4+r)
      const uint32_t bits0 = (uint32_t)(mb >> ((2 * p) * 16 + quad * 4));
      const uint32_t bits1 = (uint32_t)(mb >> ((2 * p + 1) * 16 + quad * 4));
      floatx4 sA0, sA1, sB0, sB1;
#pragma unroll
      for (int r = 0; r < 4; ++r) {
        const float b0v = ((bits0 >> r) & 1) ? NEGM : 0.f;
        const float b1v = ((bits1 >> r) & 1) ? NEGM : 0.f;
        sA0[r] = b0v; sB0[r] = b0v;
        sA1[r] = b1v; sB1[r] = b1v;
      }

      // ---- S^T for pair p: 8 MFMAs ----
      sA0 = MFMA16(kf0[p][0], aqA0, sA0, 0, 0, 0);
      sA0 = MFMA16(kf1[p][0], aqA1, sA0, 0, 0, 0);
      sB0 = MFMA16(kf0[p][0], aqB0, sB0, 0, 0, 0);
      sB0 = MFMA16(kf1[p][0], aqB1, sB0, 0, 0, 0);
      sA1 = MFMA16(kf0[p][1], aqA0, sA1, 0, 0, 0);
      sA1 = MFMA16(kf1[p][1], aqA1, sA1, 0, 0, 0);
      sB1 = MFMA16(kf0[p][1], aqB0, sB1, 0, 0, 0);
      sB1 = MFMA16(kf1[p][1], aqB1, sB1, 0, 0, 0);

      // ---- exp2 (masked -> exact 0 via underflow) + partial l + pack ----
      bf16x8 bpA, bpB;
#pragma unroll
      for (int r = 0; r < 4; ++r) {
        const float pA0 = __builtin_amdgcn_exp2f(sA0[r]);
        const float pA1 = __builtin_amdgcn_exp2f(sA1[r]);
        const float pB0 = __builtin_amdgcn_exp2f(sB0[r]);
        const float pB1 = __builtin_amdgcn_exp2f(sB1[r]);
        laccA[r] += pA0 + pA1;
        laccB[r] += pB0 + pB1;
        bpA[r] = (__bf16)pA0; bpA[4 + r] = (__bf16)pA1;
        bpB[r] = (__bf16)pB0; bpB[4 + r] = (__bf16)pB1;
      }

      // ---- O^T += V^T . P^T for pair p: 8 MFMAs ----
#pragma unroll
      for (int nd = 0; nd < 4; ++nd) {
        oA[nd] = MFMA16(vf[p][nd], bpA, oA[nd], 0, 0, 0);
        oB[nd] = MFMA16(vf[p][nd], bpB, oB[nd], 0, 0, 0);
      }
    }
    __builtin_amdgcn_s_setprio(0);
  }

  // ---- partial l reduce across quads ----
  float lA = (laccA[0] + laccA[1]) + (laccA[2] + laccA[3]);
  float lB = (laccB[0] + laccB[1]) + (laccB[2] + laccB[3]);
  lA += __shfl_xor(lA, 16); lA += __shfl_xor(lA, 32);
  lB += __shfl_xor(lB, 16); lB += __shfl_xor(lB, 32);

  // ---- K-split merge: group 1 -> LDS, group 0 adds + normalizes + stores.
  // Staging LDS is dead now. Chunk-XOR swizzle keeps b128 traffic 2-way.
  __syncthreads();  // all LDS tile reads complete before reuse
  float* sm = (float*)&Klds[0][0][0];   // 8192 floats = 32 KB
  float* sl = (float*)&Vlds[0][0][0];
  const int mbase = (wq * 64 + lane) * 32;  // 32 floats (8x16B chunks) per lane
  const int sw = lane & 7;
  if (kgrp == 1) {
#pragma unroll
    for (int nd = 0; nd < 4; ++nd) {
      *(floatx4*)&sm[mbase + ((nd ^ sw) << 2)]       = oA[nd];
      *(floatx4*)&sm[mbase + (((4 + nd) ^ sw) << 2)] = oB[nd];
    }
    sl[(wq * 64 + lane) * 2 + 0] = lA;
    sl[(wq * 64 + lane) * 2 + 1] = lB;
  }
  __syncthreads();
  if (kgrp == 0) {
    lA += sl[(wq * 64 + lane) * 2 + 0];
    lB += sl[(wq * 64 + lane) * 2 + 1];
    const float iA = 1.0f / lA, iB = 1.0f / lB;
#pragma unroll
    for (int nd = 0; nd < 4; ++nd) {
      floatx4 pA = *(const floatx4*)&sm[mbase + ((nd ^ sw) << 2)];
      floatx4 pB = *(const floatx4*)&sm[mbase + (((4 + nd) ^ sw) << 2)];
      pA += oA[nd];
      pB += oB[nd];
      float4 wv;
      wv.x = pA[0] * iA; wv.y = pA[1] * iA;
      wv.z = pA[2] * iA; wv.w = pA[3] * iA;
      *(float4*)(Ob + (size_t)(q0A + ln) * Dd + nd * 16 + quad * 4) = wv;
      wv.x = pB[0] * iB; wv.y = pB[1] * iB;
      wv.z = pB[2] * iB; wv.w = pB[3] * iB;
      *(float4*)(Ob + (size_t)(q0B + ln) * Dd + nd * 16 + quad * 4) = wv;
    }
  }
}

}  // namespace

extern "C" void kernel_launch(void* const* d_in, const int* in_sizes, int n_in,
                              void* d_out, int out_size, void* d_ws, size_t ws_size,
                              hipStream_t stream) {
  const float* Q   = (const float*)d_in[0];
  const float* K   = (const float*)d_in[1];
  const float* V   = (const float*)d_in[2];
  const int*  mask = (const int*)d_in[3];
  float* Out = (float*)d_out;

  preprocess3<<<dim3(32, 32, 2), 256, 0, stream>>>(K, V, mask, (uint8_t*)d_ws);
  attn_fused8<<<dim3(Bb * Hh, Ss / 128), 512, 0, stream>>>(Q, (const uint8_t*)d_ws, Out);
  (void)ws_size; (void)in_sizes; (void)n_in; (void)out_size;
}

// Round 4
// 135.002 us; speedup vs baseline: 1.0967x; 1.0853x over previous
//
#include <hip/hip_runtime.h>
#include <hip/hip_bf16.h>
#include <stdint.h>

namespace {

constexpr int Bb = 2;
constexpr int Hh = 16;
constexpr int Ss = 2048;
constexpr int Dd = 64;
constexpr int KT = 64;                   // keys per stored tile
constexpr int NT = Ss / KT;              // 32 stored key tiles
constexpr int TILE_BYTES = KT * Dd * 2;  // 8192 B per bf16 tile
constexpr int BH_BYTES = NT * TILE_BYTES;
constexpr size_t KPRE_BYTES = (size_t)Bb * Hh * Ss * Dd * 2;  // 8 MB
constexpr size_t VPRE_OFF = KPRE_BYTES;
constexpr size_t MASK_OFF = 2 * KPRE_BYTES;
constexpr size_t WS_NEED = MASK_OFF + (size_t)Bb * NT * 8;
constexpr int NIT = 16;                   // 128-key iterations
constexpr int IT_BYTES = 2 * TILE_BYTES;  // 16 KB per tensor per iter

typedef __bf16 bf16x8 __attribute__((ext_vector_type(8)));
typedef float floatx4 __attribute__((ext_vector_type(4)));

typedef __attribute__((address_space(1))) const unsigned int guint;
typedef __attribute__((address_space(3))) unsigned int luint;

__device__ __forceinline__ void g2lds16(const void* g, void* l) {
  __builtin_amdgcn_global_load_lds((guint*)g, (luint*)l, 16, 0, 0);
}

// ---------------- preprocess4: ZERO LDS ----------------
// R3 lesson: preprocess3's __shared__ float Vsh[64*68] (68 KB) was allocated
// for EVERY block (static LDS is per-kernel, not per-branch), capping the
// 2048 tiny blocks at 2/CU -> >=4 serialized latency-bound rounds (~40+ us).
// Fix: V transpose reads directly from global with d in the LOW lane bits:
// for fixed j, 32 lanes read 32 consecutive float2 (256 B) -- coalesced.
// Output bytes identical to preprocess3 (validated layout).
__global__ __launch_bounds__(256) void preprocess4(
    const float* __restrict__ K, const float* __restrict__ V,
    const int* __restrict__ mask, uint8_t* __restrict__ ws)
{
  const int tid = threadIdx.x;
  const int kt = blockIdx.x;
  const int bh = blockIdx.y;

  if (blockIdx.z == 0) {
    // ---- K: convert + swizzled store (both sides contiguous per wave) ----
    const int c = tid & 7;
#pragma unroll
    for (int half = 0; half < 2; ++half) {
      const int row = (tid >> 3) + half * 32;
      const float4* src = (const float4*)(K + ((size_t)bh * 2048 + kt * 64 + row) * 64 + c * 8);
      const float4 a = src[0], b2 = src[1];
      bf16x8 pk;
      pk[0] = (__bf16)a.x;  pk[1] = (__bf16)a.y;  pk[2] = (__bf16)a.z;  pk[3] = (__bf16)a.w;
      pk[4] = (__bf16)b2.x; pk[5] = (__bf16)b2.y; pk[6] = (__bf16)b2.z; pk[7] = (__bf16)b2.w;
      uint8_t* dst = ws + (size_t)bh * BH_BYTES + kt * TILE_BYTES + row * 128 + ((c ^ (row & 7)) << 4);
      *(bf16x8*)dst = pk;
    }
    if (bh == 0 && kt < 16) {  // mask ballots: 16 blocks cover Bb*Ss = 4096
      const int i = kt * 256 + tid;
      const int bb = i >> 11, key = i & 2047;
      const unsigned long long bal = __ballot(mask[bb * 2048 + key] != 0);
      if ((key & 63) == 0)
        ((unsigned long long*)(ws + MASK_OFF))[bb * NT + (key >> 6)] = bal;
    }
    return;
  }

  // ---- V: direct transposed gather (no LDS) ----
  // thread = c16 (chunk 0..7) x d2 (d-pair 0..31). Same output as before:
  // chunk c16=(q<<1)|s2 of row d holds keys {k0..k0+3, k0+16..k0+19},
  // k0 = 32*s2 + 4*q, stored at byte (c16 ^ (d&7))*16 of row d.
  const int d2  = tid & 31;
  const int c16 = tid >> 5;
  const int s2 = c16 & 1, q = c16 >> 1;
  const int k0 = 32 * s2 + 4 * q;
  const float* vbase = V + ((size_t)bh * 2048 + kt * 64) * 64;
  float2 col[8];
#pragma unroll
  for (int j = 0; j < 4; ++j) {
    col[j]     = *(const float2*)(vbase + (size_t)(k0 + j) * 64 + 2 * d2);
    col[4 + j] = *(const float2*)(vbase + (size_t)(k0 + 16 + j) * 64 + 2 * d2);
  }
#pragma unroll
  for (int h = 0; h < 2; ++h) {
    const int d = 2 * d2 + h;
    bf16x8 pv;
#pragma unroll
    for (int j = 0; j < 4; ++j) {
      pv[j]     = (__bf16)(h ? col[j].y     : col[j].x);
      pv[4 + j] = (__bf16)(h ? col[4 + j].y : col[4 + j].x);
    }
    uint8_t* dst = ws + VPRE_OFF + (size_t)bh * BH_BYTES + kt * TILE_BYTES + d * 128 + ((c16 ^ (d & 7)) << 4);
    *(bf16x8*)dst = pv;
  }
}

// -10000 * log2(e): reference's masked_fill value, in exp2 domain.
#define NEGM (-14426.950408889634f)
#define MFMA16 __builtin_amdgcn_mfma_f32_16x16x32_bf16

// ---------------- fused attention (R1 attn_fused7, best measured 54.7us) --
// S^T = K.Q^T, mask-as-C-bias, PV K=32, dual q-streams sharing LDS reads,
// g2lds double-buffer, subtile-pair software pipeline, setprio around compute.
// R2/R3 lesson: in-block K-split (8-wave blocks) regressed both at (512,4)
// (64-reg cap -> 33 MB spill traffic) and (512,2) (76-reg conservative
// codegen, no occupancy gain). 4-wave blocks + 112 VGPR is the sweet spot.
__global__ __launch_bounds__(256, 2) void attn_fused7(
    const float* __restrict__ Q, const uint8_t* __restrict__ ws,
    float* __restrict__ Out)
{
  const int tid  = threadIdx.x;
  const int wave = tid >> 6;
  const int lane = tid & 63;
  const int ln   = lane & 15;
  const int quad = lane >> 4;

  const int bh   = blockIdx.x;  // 0..31 (same bh -> same XCD for L2 reuse)
  const int qblk = blockIdx.y;  // 0..15
  const int b    = bh >> 4;

  const float* Qb = Q + (size_t)bh * Ss * Dd;
  float*       Ob = Out + (size_t)bh * Ss * Dd;
  const uint8_t* Kpre = ws + (size_t)bh * BH_BYTES;
  const uint8_t* Vpre = ws + VPRE_OFF + (size_t)bh * BH_BYTES;
  const unsigned long long* Mbits = (const unsigned long long*)(ws + MASK_OFF) + b * NT;

  __shared__ __align__(16) __bf16 Klds[2][128 * Dd];   // 2 x 16 KB
  __shared__ __align__(16) __bf16 Vlds[2][128 * Dd];   // 2 x 16 KB

  const int q0A = qblk * 128 + wave * 32;
  const int q0B = q0A + 16;

  // Q B-frags, pre-scaled by 1/8*log2(e). B[k=quad*8+j][n=ln] = Qs[q][d].
  const float QS = 0.125f * 1.44269504088896340736f;
  bf16x8 aqA0, aqA1, aqB0, aqB1;
  {
    const float* qpA = Qb + (size_t)(q0A + ln) * Dd + quad * 8;
    const float* qpB = Qb + (size_t)(q0B + ln) * Dd + quad * 8;
#pragma unroll
    for (int j = 0; j < 8; ++j) {
      aqA0[j] = (__bf16)(qpA[j] * QS);
      aqA1[j] = (__bf16)(qpA[32 + j] * QS);
      aqB0[j] = (__bf16)(qpB[j] * QS);
      aqB1[j] = (__bf16)(qpB[32 + j] * QS);
    }
  }

  floatx4 oA[4], oB[4];    // O^T C-layout: d = nd*16+quad*4+r, q = ln
  floatx4 laccA = (floatx4){0.f, 0.f, 0.f, 0.f};
  floatx4 laccB = (floatx4){0.f, 0.f, 0.f, 0.f};
#pragma unroll
  for (int nd = 0; nd < 4; ++nd) {
    oA[nd] = (floatx4){0.f, 0.f, 0.f, 0.f};
    oB[nd] = (floatx4){0.f, 0.f, 0.f, 0.f};
  }

  const int swz0 = (quad ^ (ln & 7)) << 4;
  const int swz1 = ((quad + 4) ^ (ln & 7)) << 4;
  const int soff = wave * 4096 + lane * 16;

  // prologue: stage iter 0 into buffer 0
#pragma unroll
  for (int i = 0; i < 4; ++i) {
    g2lds16(Kpre + soff + i * 1024, (uint8_t*)Klds[0] + soff + i * 1024);
    g2lds16(Vpre + soff + i * 1024, (uint8_t*)Vlds[0] + soff + i * 1024);
  }

  for (int kt2 = 0; kt2 < NIT; ++kt2) {
    const int cur = kt2 & 1;
    __syncthreads();  // closes prev-iter reads + drains this buf's g2lds

    if (kt2 + 1 < NIT) {
      const uint8_t* kg = Kpre + (kt2 + 1) * IT_BYTES;
      const uint8_t* vg = Vpre + (kt2 + 1) * IT_BYTES;
      uint8_t* kl = (uint8_t*)Klds[cur ^ 1];
      uint8_t* vl = (uint8_t*)Vlds[cur ^ 1];
#pragma unroll
      for (int i = 0; i < 4; ++i) {
        g2lds16(kg + soff + i * 1024, kl + soff + i * 1024);
        g2lds16(vg + soff + i * 1024, vl + soff + i * 1024);
      }
    }

    const unsigned long long mb0 = Mbits[2 * kt2];
    const unsigned long long mb1 = Mbits[2 * kt2 + 1];

    const uint8_t* Kb = (const uint8_t*)Klds[cur];
    const uint8_t* Vb = (const uint8_t*)Vlds[cur];

    // fragment read helpers (fully unrolled -> constant offsets)
    auto loadK = [&](int sub, bf16x8& b0, bf16x8& b1) {
      const uint8_t* krow = Kb + (sub >> 2) * 8192 + ((sub & 3) * 16 + ln) * 128;
      b0 = *(const bf16x8*)(krow + swz0);
      b1 = *(const bf16x8*)(krow + swz1);
    };
    auto loadV = [&](int p, bf16x8* w) {  // pair p: T=p>>1, s2=p&1
      const int T = p >> 1, s2 = p & 1;
#pragma unroll
      for (int nd = 0; nd < 4; ++nd) {
        const uint8_t* vrow = Vb + T * 8192 + (nd * 16 + ln) * 128;
        w[nd] = *(const bf16x8*)(vrow + (((quad * 2 + s2) ^ (ln & 7)) << 4));
      }
    };

    __builtin_amdgcn_s_setprio(1);

    // register double-buffered fragment pipeline
    bf16x8 kf0[2][2], kf1[2][2];  // [p&1][subtile-in-pair]
    bf16x8 vf[2][4];              // [p&1][nd]
    loadK(0, kf0[0][0], kf1[0][0]);
    loadK(1, kf0[0][1], kf1[0][1]);
    loadV(0, vf[0]);

#pragma unroll
    for (int p = 0; p < 4; ++p) {
      const int cb = p & 1, nb = cb ^ 1;

      // read-ahead: pair p+1 fragments (hidden under pair p compute)
      if (p < 3) {
        loadK(2 * p + 2, kf0[nb][0], kf1[nb][0]);
        loadK(2 * p + 3, kf0[nb][1], kf1[nb][1]);
        loadV(p + 1, vf[nb]);
      }

      // per-key mask bias for subtiles 2p, 2p+1 (key = 16*sub+quad*4+r)
      const unsigned long long mbx = (p & 2) ? mb1 : mb0;
      const uint32_t bits0 = (uint32_t)(mbx >> ((((2 * p) & 3) * 16) + quad * 4));
      const uint32_t bits1 = (uint32_t)(mbx >> ((((2 * p + 1) & 3) * 16) + quad * 4));
      floatx4 sA0, sA1, sB0, sB1;
#pragma unroll
      for (int r = 0; r < 4; ++r) {
        const float b0v = ((bits0 >> r) & 1) ? NEGM : 0.f;
        const float b1v = ((bits1 >> r) & 1) ? NEGM : 0.f;
        sA0[r] = b0v; sB0[r] = b0v;
        sA1[r] = b1v; sB1[r] = b1v;
      }

      // ---- S^T for pair p: 8 MFMAs ----
      sA0 = MFMA16(kf0[cb][0], aqA0, sA0, 0, 0, 0);
      sA0 = MFMA16(kf1[cb][0], aqA1, sA0, 0, 0, 0);
      sB0 = MFMA16(kf0[cb][0], aqB0, sB0, 0, 0, 0);
      sB0 = MFMA16(kf1[cb][0], aqB1, sB0, 0, 0, 0);
      sA1 = MFMA16(kf0[cb][1], aqA0, sA1, 0, 0, 0);
      sA1 = MFMA16(kf1[cb][1], aqA1, sA1, 0, 0, 0);
      sB1 = MFMA16(kf0[cb][1], aqB0, sB1, 0, 0, 0);
      sB1 = MFMA16(kf1[cb][1], aqB1, sB1, 0, 0, 0);

      // ---- exp2 (masked -> exact 0 via underflow) + partial l + pack ----
      bf16x8 bpA, bpB;
#pragma unroll
      for (int r = 0; r < 4; ++r) {
        const float pA0 = __builtin_amdgcn_exp2f(sA0[r]);
        const float pA1 = __builtin_amdgcn_exp2f(sA1[r]);
        const float pB0 = __builtin_amdgcn_exp2f(sB0[r]);
        const float pB1 = __builtin_amdgcn_exp2f(sB1[r]);
        laccA[r] += pA0 + pA1;
        laccB[r] += pB0 + pB1;
        bpA[r] = (__bf16)pA0; bpA[4 + r] = (__bf16)pA1;
        bpB[r] = (__bf16)pB0; bpB[4 + r] = (__bf16)pB1;
      }

      // ---- O^T += V^T . P^T for pair p: 8 MFMAs ----
#pragma unroll
      for (int nd = 0; nd < 4; ++nd) {
        oA[nd] = MFMA16(vf[cb][nd], bpA, oA[nd], 0, 0, 0);
        oB[nd] = MFMA16(vf[cb][nd], bpB, oB[nd], 0, 0, 0);
      }
    }
    __builtin_amdgcn_s_setprio(0);
  }

  // ---- epilogue: reduce l across quads, normalize, store ----
  float lA = (laccA[0] + laccA[1]) + (laccA[2] + laccA[3]);
  float lB = (laccB[0] + laccB[1]) + (laccB[2] + laccB[3]);
  lA += __shfl_xor(lA, 16); lA += __shfl_xor(lA, 32);
  lB += __shfl_xor(lB, 16); lB += __shfl_xor(lB, 32);
  const float iA = 1.0f / lA, iB = 1.0f / lB;
#pragma unroll
  for (int nd = 0; nd < 4; ++nd) {
    float4 wv;
    wv.x = oA[nd][0] * iA; wv.y = oA[nd][1] * iA;
    wv.z = oA[nd][2] * iA; wv.w = oA[nd][3] * iA;
    *(float4*)(Ob + (size_t)(q0A + ln) * Dd + nd * 16 + quad * 4) = wv;
    wv.x = oB[nd][0] * iB; wv.y = oB[nd][1] * iB;
    wv.z = oB[nd][2] * iB; wv.w = oB[nd][3] * iB;
    *(float4*)(Ob + (size_t)(q0B + ln) * Dd + nd * 16 + quad * 4) = wv;
  }
}

}  // namespace

extern "C" void kernel_launch(void* const* d_in, const int* in_sizes, int n_in,
                              void* d_out, int out_size, void* d_ws, size_t ws_size,
                              hipStream_t stream) {
  const float* Q   = (const float*)d_in[0];
  const float* K   = (const float*)d_in[1];
  const float* V   = (const float*)d_in[2];
  const int*  mask = (const int*)d_in[3];
  float* Out = (float*)d_out;

  preprocess4<<<dim3(32, 32, 2), 256, 0, stream>>>(K, V, mask, (uint8_t*)d_ws);
  attn_fused7<<<dim3(Bb * Hh, Ss / 128), 256, 0, stream>>>(Q, (const uint8_t*)d_ws, Out);
  (void)ws_size; (void)in_sizes; (void)n_in; (void)out_size;
}